// Round 12
// baseline (608.275 us; speedup 1.0000x reference)
//
#include <hip/hip_runtime.h>

// ===========================================================================
// ViewGCNEncoder r27 = r26 with the panel-SpMM rebuilt at instruction parity.
// r26 counters: FETCH 208->94.7MB CONFIRMED panel-L2-residency, but scalar
// 2B/lane gathers quadrupled dynamic instructions (VALU 53%) -> 158us.
// Fix: wave=row; per 8-edge iter lane j = edge-slot (j>>3) x feat-quad
// ((j&7)*4): ONE wave-wide u32x2 load covers 8 edges x 32 feats (same
// instr/feat as spmm8), 8 contiguous lanes read each edge's full 64B panel
// line. shfl_xor(8,16,32) reduces edge slots; lanes 0-7 write.
// Kept: panel-major GEMM stores, atomic-free scatter, lookback scan,
// pass2+GEMM1 fusion. 10 launches. Workspace ~89 MB.
// ===========================================================================

typedef unsigned short ushort_t;
typedef __attribute__((ext_vector_type(8))) short bf16x8;   // 8 bf16 = 4 VGPRs
typedef __attribute__((ext_vector_type(4))) float f32x4;
typedef __attribute__((ext_vector_type(2))) unsigned int u32x2;
typedef __attribute__((ext_vector_type(4))) unsigned int u32x4;

__device__ __forceinline__ float bf2f(ushort_t u) {
  return __uint_as_float(((unsigned int)u) << 16);
}
__device__ __forceinline__ ushort_t f2bf(float f) {
  unsigned int u = __float_as_uint(f);
  return (ushort_t)((u + 0x7FFFu + ((u >> 16) & 1u)) >> 16);  // RNE
}
__device__ __forceinline__ float read_f(const void* p, int fm, size_t i) {
  return fm ? bf2f(((const ushort_t*)p)[i]) : ((const float*)p)[i];
}

// fragment-order offset: tile-major 16-row tiles; within tile kc-chunk(32 k)
// then lane-linear (lane = (m&15)+16*((k>>3)&3), 8 elems each).
__device__ __forceinline__ size_t frag_off(int m, int k, int K) {
  return (size_t)(m >> 4) * 16 * K + ((size_t)(k >> 5) << 9) +
         (((k >> 3) & 3) << 7) + ((m & 15) << 3) + (k & 7);
}

// ---------------- prep: sniff (0-2) + W/bias convert (3-34) + zero (35+) ---
__global__ void prep_kernel(const void* __restrict__ x,
                            const void* __restrict__ m1,
                            const void* __restrict__ m2,
                            int* __restrict__ modes,
                            int* __restrict__ zero_region, int zn,
                            const void* __restrict__ W1, const void* __restrict__ W2,
                            const void* __restrict__ W3,
                            const void* __restrict__ b1, const void* __restrict__ b2,
                            const void* __restrict__ b3,
                            ushort_t* __restrict__ whi, ushort_t* __restrict__ wlo,
                            float* __restrict__ biasf,
                            int n1, int n2, int n3, int h1, int h2, int h3,
                            int K1, int K2, int K3) {
  if (blockIdx.x == 0) {
    __shared__ int bfok;
    if (threadIdx.x == 0) bfok = 1;
    __syncthreads();
    for (int i = threadIdx.x; i < 8192; i += blockDim.x) {
      ushort_t h = ((const ushort_t*)x)[i];
      int e = (h >> 7) & 0xFF;
      if (!(h == 0 || (e >= 95 && e <= 133))) atomicAnd(&bfok, 0);
    }
    __syncthreads();
    if (threadIdx.x == 0) modes[0] = bfok;   // 1=bf16, 0=f32
  } else if (blockIdx.x <= 2) {
    const void* p = (blockIdx.x == 1) ? m1 : m2;
    __shared__ int ok[4];  // [i32, f32, bf16, u8]
    if (threadIdx.x < 4) ok[threadIdx.x] = 1;
    __syncthreads();
    for (int i = threadIdx.x; i < 4096; i += blockDim.x) {
      unsigned int w = ((const unsigned int*)p)[i];
      if (!(w == 0u || w == 1u)) atomicAnd(&ok[0], 0);
      if (!(w == 0u || w == 0x3F800000u)) atomicAnd(&ok[1], 0);
      unsigned int h16 = w >> 16, l16 = w & 0xFFFFu;
      if (!((h16 == 0u || h16 == 0x3F80u) && (l16 == 0u || l16 == 0x3F80u)))
        atomicAnd(&ok[2], 0);
      if (((w | (w >> 8) | (w >> 16) | (w >> 24)) & 0xFEu) != 0u) atomicAnd(&ok[3], 0);
    }
    __syncthreads();
    if (threadIdx.x == 0)
      modes[blockIdx.x] = ok[0] ? 1 : (ok[1] ? 2 : (ok[2] ? 3 : 0));
  } else if (blockIdx.x < 35) {
    // W split + bias convert; self-sniff x dtype (weights share x's dtype)
    __shared__ int bfok;
    if (threadIdx.x == 0) bfok = 1;
    __syncthreads();
    for (int i = threadIdx.x; i < 8192; i += blockDim.x) {
      ushort_t h = ((const ushort_t*)x)[i];
      int e = (h >> 7) & 0xFF;
      if (!(h == 0 || (e >= 95 && e <= 133))) atomicAnd(&bfok, 0);
    }
    __syncthreads();
    int fm = bfok;
    int wtot = n1 + n2 + n3;
    int total = wtot + h1 + h2 + h3;
    for (int i = (blockIdx.x - 3) * 256 + threadIdx.x; i < total; i += 32 * 256) {
      if (i < wtot) {
        const void* src; int j, K; size_t base;
        if (i < n1) { src = W1; j = i; K = K1; base = 0; }
        else if (i < n1 + n2) { src = W2; j = i - n1; K = K2; base = n1; }
        else { src = W3; j = i - n1 - n2; K = K3; base = (size_t)n1 + n2; }
        int n = j / K, k = j - n * K;
        float v = read_f(src, fm, j);
        ushort_t h = f2bf(v);
        size_t o = base + frag_off(n, k, K);
        whi[o] = h;
        wlo[o] = f2bf(v - bf2f(h));
      } else {
        int k = i - wtot;
        const void* src; int j;
        if (k < h1) { src = b1; j = k; }
        else if (k < h1 + h2) { src = b2; j = k - h1; }
        else { src = b3; j = k - h1 - h2; }
        biasf[k] = read_f(src, fm, j);
      }
    }
  } else {
    int i = (blockIdx.x - 35) * blockDim.x + threadIdx.x;
    int stride = (gridDim.x - 35) * blockDim.x;
    for (; i < zn; i += stride) zero_region[i] = 0;
  }
}

// ---------------- pass 1: tile-binning, LDS-staged flush (no edge atomics) --
__global__ void hist_bin_kernel(
    const int* __restrict__ rows, const int* __restrict__ cols,
    const void* __restrict__ vals, const int* __restrict__ fm_p,
    int* __restrict__ h8, int* __restrict__ cnt_ovf, int* __restrict__ binfill,
    int2* __restrict__ bins, int cap, int use_bins, int4* __restrict__ ovf,
    int E, int Nrows, const void* __restrict__ x, ushort_t* __restrict__ xbf,
    int K1, int nx) {
  int fm = *fm_p;
  const int BIN_BLOCKS = 1024;
  if (blockIdx.x < BIN_BLOCKS) {
    int xcd = blockIdx.x & 7;
    if (use_bins) {
      __shared__ int hist[8];
      __shared__ int gbase[8];
      __shared__ int pfx[8];
      __shared__ int2 stage[1024];
      int tid = threadIdx.x;
      for (int tb = blockIdx.x; tb * 1024 < E; tb += BIN_BLOCKS) {
        int base = tb * 1024;
        if (tid < 8) hist[tid] = 0;
        __syncthreads();
        int rr[4], cc[4], pp[4], rk[4]; float vv[4];
#pragma unroll
        for (int j = 0; j < 4; ++j) {
          int i = base + j * 256 + tid;
          if (i < E) {
            rr[j] = rows[i]; cc[j] = cols[i]; vv[j] = read_f(vals, fm, i);
            pp[j] = rr[j] >> 13;                   // partition 0..7
            rk[j] = atomicAdd(&hist[pp[j]], 1);    // LDS rank
          } else {
            pp[j] = -1;
          }
        }
        __syncthreads();
        if (tid == 0) {
          int s = 0;
#pragma unroll
          for (int q = 0; q < 8; ++q) { pfx[q] = s; s += hist[q]; }
        }
        if (tid < 8)
          gbase[tid] = atomicAdd(&binfill[(xcd << 4) + tid], hist[tid]);
        __syncthreads();
        // stage partition-sorted
#pragma unroll
        for (int j = 0; j < 4; ++j) {
          if (pp[j] >= 0)
            stage[pfx[pp[j]] + rk[j]] =
                make_int2((rr[j] << 16) | cc[j], __float_as_int(vv[j]));
        }
        __syncthreads();
        // coalesced flush
        int total = pfx[7] + hist[7];
        for (int k = tid; k < total; k += 256) {
          int p = 0;
#pragma unroll
          for (int q = 1; q < 8; ++q) p += (k >= pfx[q]);
          int2 ent = stage[k];
          int pos = gbase[p] + (k - pfx[p]);
          if (pos < cap) {
            bins[(size_t)((xcd << 3) + p) * cap + pos] = ent;
          } else {  // overflow (skewed rows): pre-assign rank, append to ovf
            int r = ((unsigned int)ent.x) >> 16;
            int orank = atomicAdd(&cnt_ovf[r], 1);
            int op = atomicAdd(&binfill[128], 1);
            ovf[op] = make_int4(r, ent.x & 0xFFFF, ent.y, orank);
          }
        }
        __syncthreads();            // protect pfx/hist before next tile
      }
    } else {
      // fallback (N > 65535): sharded atomic hist; pass 2 direct-scatters
      int* cnt_s = h8 + (size_t)xcd * Nrows;
      int i = blockIdx.x * blockDim.x + threadIdx.x;
      int stride = BIN_BLOCKS * blockDim.x;
      for (; i < E; i += stride) atomicAdd(&cnt_s[rows[i]], 1);
    }
  } else {
    // x -> bf16 frag conversion (only when x is f32)
    if (fm == 1) return;
    int nx4 = nx / 4;
    int i = (blockIdx.x - BIN_BLOCKS) * blockDim.x + threadIdx.x;
    int stride = (gridDim.x - BIN_BLOCKS) * blockDim.x;
    for (; i < nx4; i += stride) {
      int m = i / (K1 / 4);
      int k0 = (i - m * (K1 / 4)) * 4;
      f32x4 v = ((const f32x4*)x)[i];
      ushort_t p0 = f2bf(v[0]), p1 = f2bf(v[1]), p2 = f2bf(v[2]), p3 = f2bf(v[3]);
      size_t o = frag_off(m, k0, K1);
      *(u32x2*)(xbf + o) = (u32x2){
          (unsigned int)p0 | ((unsigned int)p1 << 16),
          (unsigned int)p2 | ((unsigned int)p3 << 16)};
    }
  }
}

// ---------------- pass 1.5: per-(xcd,partition) LDS histogram -> h8 ---------
__global__ __launch_bounds__(256) void count_kernel(
    const int2* __restrict__ bins, const int* __restrict__ binfill,
    int cap, int* __restrict__ h8, int Nrows, int use_bins) {
  if (!use_bins) return;
  int x = blockIdx.x >> 3, p = blockIdx.x & 7;
  __shared__ int hist[8192];
  for (int i = threadIdx.x; i < 8192; i += 256) hist[i] = 0;
  __syncthreads();
  int n = binfill[x * 16 + p];
  if (n > cap) n = cap;
  const int2* bp = bins + (size_t)((x << 3) + p) * cap;
  for (int e = threadIdx.x; e < n; e += 256) {
    int r = ((unsigned int)bp[e].x) >> 16;
    atomicAdd(&hist[r & 8191], 1);
  }
  __syncthreads();
  int r0 = p << 13;
  for (int i = threadIdx.x; i < 8192; i += 256) {
    int r = r0 + i;
    if (r < Nrows) h8[(size_t)x * Nrows + r] = hist[i];
  }
}

// ---------------- single-pass scan: shard-sum + lookback + cursor bases -----
__global__ __launch_bounds__(256) void scan_fused_kernel(
    const int* __restrict__ h8, const int* __restrict__ cnt_ovf,
    int* __restrict__ pub, int* __restrict__ row_start,
    int* __restrict__ sb8, int n) {
  int b = blockIdx.x, t = threadIdx.x;
  int i = b * 256 + t;
  int hx[8];
  int v = 0, ov = 0;
  if (i < n) {
#pragma unroll
    for (int x = 0; x < 8; ++x) { hx[x] = h8[(size_t)x * n + i]; v += hx[x]; }
    ov = cnt_ovf[i];
  } else {
#pragma unroll
    for (int x = 0; x < 8; ++x) hx[x] = 0;
  }
  int vt = v + ov;
  __shared__ int s[256];
  s[t] = vt;
  __syncthreads();
  for (int off = 1; off < 256; off <<= 1) {
    int a_ = s[t];
    int y_ = (t >= off) ? s[t - off] : 0;
    __syncthreads();
    s[t] = a_ + y_;
    __syncthreads();
  }
  int incl = s[t];
  int total = s[255];
  if (t == 0)
    __hip_atomic_store(&pub[b], (total << 1) | 1, __ATOMIC_RELEASE,
                       __HIP_MEMORY_SCOPE_AGENT);
  int contrib = 0;
  for (int t0 = t; t0 < b; t0 += 256) {
    int p;
    do {
      p = __hip_atomic_load(&pub[t0], __ATOMIC_ACQUIRE,
                            __HIP_MEMORY_SCOPE_AGENT);
    } while (!(p & 1));
    contrib += (p >> 1);
  }
  __syncthreads();                 // s[] reuse barrier
  s[t] = contrib;
  __syncthreads();
  for (int off = 128; off > 0; off >>= 1) {
    if (t < off) s[t] += s[t + off];
    __syncthreads();
  }
  int base = s[0];
  int rs = base + incl - vt;       // exclusive
  if (i < n) {
    row_start[i] = rs;
    int acc = rs;
#pragma unroll
    for (int x = 0; x < 8; ++x) { sb8[(size_t)x * n + i] = acc; acc += hx[x]; }
    sb8[(size_t)8 * n + i] = acc;  // ovf base
  }
  if (i == n - 1) row_start[n] = base + incl;
}

// ---------------- GEMM body (r15 core, PANEL-MAJOR store) -------------------
template<int KC>
__device__ __forceinline__ void load_afrag(const ushort_t* __restrict__ A,
                                           const ushort_t* __restrict__ Xrow,
                                           bool rowA, int mtile, int K,
                                           int lane, int mr, int quad, int M,
                                           bf16x8* dst) {
  if (rowA) {
    int rr = mtile * 16 + mr;
    if (rr >= M) rr = M - 1;
    const ushort_t* ap = Xrow + (size_t)rr * K + quad * 8;
#pragma unroll
    for (int kc = 0; kc < KC; ++kc) dst[kc] = *(const bf16x8*)(ap + kc * 32);
  } else {
    const ushort_t* ap = A + (size_t)mtile * 16 * K + lane * 8;
#pragma unroll
    for (int kc = 0; kc < KC; ++kc) dst[kc] = *(const bf16x8*)(ap + kc * 512);
  }
}

template<int KC>
__device__ __forceinline__ void gemm_dev(
    int vbid, int nblk, int tid,
    const ushort_t* __restrict__ A, const ushort_t* __restrict__ Xrow, int fm,
    const ushort_t* __restrict__ Whi, const ushort_t* __restrict__ Wlo,
    const float* __restrict__ bias, ushort_t* __restrict__ g, int Np,
    int M, int nct) {
  const int K = KC * 32;
  int wave = tid >> 6, lane = tid & 63;
  int gw = vbid * 4 + wave;
  int NW = nblk * 4;
  int mr = lane & 15, quad = lane >> 4;
  int ct = gw % nct;
  int nrt = (M + 15) >> 4;
  int ntasks = nct * nrt;
  if (gw >= ntasks) return;

  bool rowA = (Xrow != nullptr) && (fm != 0);

  bf16x8 wh[KC], wl[KC];
  {
    const ushort_t* wp = Whi + (size_t)ct * 16 * K + lane * 8;
    const ushort_t* wq = Wlo + (size_t)ct * 16 * K + lane * 8;
#pragma unroll
    for (int kc = 0; kc < KC; ++kc) {
      wh[kc] = *(const bf16x8*)(wp + kc * 512);
      wl[kc] = *(const bf16x8*)(wq + kc * 512);
    }
  }
  int col = ct * 16 + mr;
  float bv = bias[col];
  // panel-major G destination: panel = col>>5, within-panel col&31
  ushort_t* gp = g + (size_t)(col >> 5) * Np * 32 + (col & 31);

  int task = gw;
  bf16x8 af[KC];
  load_afrag<KC>(A, Xrow, rowA, task / nct, K, lane, mr, quad, M, af);

#pragma unroll 1
  for (;;) {
    int next = task + NW;
    bool has_next = next < ntasks;
    bf16x8 afn[KC];
    if (has_next)
      load_afrag<KC>(A, Xrow, rowA, next / nct, K, lane, mr, quad, M, afn);

    f32x4 acc[4];
#pragma unroll
    for (int t = 0; t < 4; ++t) acc[t] = (f32x4){0.f, 0.f, 0.f, 0.f};
#pragma unroll
    for (int kc = 0; kc < KC; ++kc) {
      acc[(2 * kc) & 3] = __builtin_amdgcn_mfma_f32_16x16x32_bf16(af[kc], wh[kc], acc[(2 * kc) & 3], 0, 0, 0);
      acc[(2 * kc + 1) & 3] = __builtin_amdgcn_mfma_f32_16x16x32_bf16(af[kc], wl[kc], acc[(2 * kc + 1) & 3], 0, 0, 0);
    }
    int m0 = (task / nct) * 16;
#pragma unroll
    for (int r = 0; r < 4; ++r) {
      int row = m0 + quad * 4 + r;
      float s = ((acc[0][r] + acc[1][r]) + (acc[2][r] + acc[3][r])) + bv;
      if (row < M) gp[(size_t)row * 32] = f2bf(s);
    }
    if (!has_next) break;
#pragma unroll
    for (int kc = 0; kc < KC; ++kc) af[kc] = afn[kc];
    task = next;
  }
}

template<int KC>
__global__ __launch_bounds__(256) void gemm_breg_kernel(
    const ushort_t* __restrict__ A,
    const ushort_t* __restrict__ Xrow, const int* __restrict__ fm_p,
    const ushort_t* __restrict__ Whi, const ushort_t* __restrict__ Wlo,
    const float* __restrict__ bias, ushort_t* __restrict__ g, int Np,
    int M, int nct) {
  gemm_dev<KC>(blockIdx.x, gridDim.x, threadIdx.x, A, Xrow, *fm_p,
               Whi, Wlo, bias, g, Np, M, nct);
}

// ---------------- pass 2 (atomic-free scatter, blocks 0..63) + GEMM-1 -------
__global__ __launch_bounds__(256) void scatter_gemm_kernel(
    const int2* __restrict__ bins, const int* __restrict__ binfill,
    const int* __restrict__ row_start, int* __restrict__ fill,
    const int* __restrict__ sb8, int Nrows,
    int2* __restrict__ ecv, int cap, const int4* __restrict__ ovf,
    const int* __restrict__ rows, const int* __restrict__ cols,
    const void* __restrict__ vals, const int* __restrict__ fm_p,
    int use_bins, int E,
    const ushort_t* __restrict__ A, const ushort_t* __restrict__ Xrow,
    const ushort_t* __restrict__ Whi, const ushort_t* __restrict__ Wlo,
    const float* __restrict__ bias, ushort_t* __restrict__ g, int Np,
    int M, int nct) {
  __shared__ int sbl[8192];
  if (blockIdx.x >= 64) {
    gemm_dev<8>(blockIdx.x - 64, 1024, threadIdx.x, A, Xrow, *fm_p,
                Whi, Wlo, bias, g, Np, M, nct);
    return;
  }
  if (use_bins) {
    int x = blockIdx.x >> 3, p = blockIdx.x & 7;
    int r0 = p << 13;
    for (int i = threadIdx.x; i < 8192; i += 256) {
      int r = r0 + i;
      sbl[i] = (r < Nrows) ? sb8[(size_t)x * Nrows + r] : 0;
    }
    __syncthreads();
    int n = binfill[x * 16 + p];
    if (n > cap) n = cap;
    const int2* bp = bins + (size_t)((x << 3) + p) * cap;
    for (int e = threadIdx.x; e < n; e += 256) {
      int2 ent = bp[e];
      int r = ((unsigned int)ent.x) >> 16;
      int pos = atomicAdd(&sbl[r & 8191], 1);     // LDS cursor, no global RMW
      ecv[pos] = make_int2(ent.x & 0xFFFF, ent.y);
    }
    // ovf drain (rank pre-assigned in pass 1; no atomics)
    int ovfn = binfill[128];
    for (int e = blockIdx.x * 256 + (int)threadIdx.x; e < ovfn; e += 64 * 256) {
      int4 t = ovf[e];
      ecv[sb8[(size_t)8 * Nrows + t.x] + t.w] = make_int2(t.y, t.z);
    }
  } else {
    int fm = *fm_p;
    for (int i = blockIdx.x * 256 + (int)threadIdx.x; i < E; i += 64 * 256) {
      int r = rows[i];
      int pos = atomicAdd(&fill[r], 1);
      ecv[row_start[r] + pos] = make_int2(cols[i], __float_as_int(read_f(vals, fm, i)));
    }
  }
}

// ---------------- SpMM v11: panel-major, instruction-parity gathers ---------
// Block = 4 rows (4 waves) x 32-feat panel; panel = blockIdx % npanel (one
// XCD's L2 holds the 3.2MB panel). Wave = row; per 8-edge iter lane j =
// edge-slot (j>>3) x feat-quad ((j&7)*4): one u32x2 load covers 8 edges x
// 32 feats; 8 contiguous lanes read each edge's 64B panel line. shfl_xor
// (8,16,32) reduces edge slots; lanes 0-7 hold 4 feats each.
// MODE 1: leaky+mask -> bf16 frag (LDS stage, 64B quad segments).
// MODE 0: f32 row-major out (lanes 0-7 write f32x4 = 128B contiguous).
template<int MODE>
__global__ __launch_bounds__(256) void spmmp_kernel(
    const int* __restrict__ row_start, const int2* __restrict__ ecv,
    const ushort_t* __restrict__ Gp, int D, int Np,
    const void* __restrict__ mask, const int* __restrict__ mmode_p,
    void* __restrict__ outp, int N, int npanel) {
  __shared__ ushort_t stage[128];          // 4 rows x 32 feats (MODE 1)
  int p = blockIdx.x % npanel;
  int rg = blockIdx.x / npanel;
  int wave = threadIdx.x >> 6, lane = threadIdx.x & 63;
  int es = lane >> 3;                      // edge slot 0..7
  int fq = (lane & 7) * 4;                 // feature quad base 0..28
  int r = rg * 4 + wave;
  bool active = r < N;
  const ushort_t* G0 = Gp + (size_t)p * Np * 32;
  float a0 = 0.f, a1 = 0.f, a2 = 0.f, a3 = 0.f;

  // hoisted mask load (writer lanes 0-7: 4 feats each)
  bool keep0 = true, keep1 = true, keep2 = true, keep3 = true;
  if (MODE == 1 && active && lane < 8) {
    size_t om = (size_t)r * D + p * 32 + lane * 4;
    int mm = *mmode_p;
    if (mm == 1 || mm == 2) {
      u32x4 mv = *(const u32x4*)((const unsigned int*)mask + om);
      keep0 = mv[0] != 0u; keep1 = mv[1] != 0u;
      keep2 = mv[2] != 0u; keep3 = mv[3] != 0u;
    } else if (mm == 3) {
      u32x2 mv = *(const u32x2*)((const ushort_t*)mask + om);
      keep0 = (mv[0] & 0xFFFFu) != 0u; keep1 = (mv[0] >> 16) != 0u;
      keep2 = (mv[1] & 0xFFFFu) != 0u; keep3 = (mv[1] >> 16) != 0u;
    } else {
      unsigned int mv = *(const unsigned int*)((const unsigned char*)mask + om);
      keep0 = (mv & 0xFFu) != 0u;         keep1 = ((mv >> 8) & 0xFFu) != 0u;
      keep2 = ((mv >> 16) & 0xFFu) != 0u; keep3 = (mv >> 24) != 0u;
    }
  }

  if (active) {
    int e  = __builtin_amdgcn_readfirstlane(row_start[r]);
    int e1 = __builtin_amdgcn_readfirstlane(row_start[r + 1]);
    for (; e + 8 <= e1; e += 8) {
      int2 cv = ecv[e + es];
      float v = __int_as_float(cv.y);
      u32x2 g = *(const u32x2*)(G0 + (size_t)cv.x * 32 + fq);
      a0 += v * bf2f((ushort_t)g[0]);
      a1 += v * bf2f((ushort_t)(g[0] >> 16));
      a2 += v * bf2f((ushort_t)g[1]);
      a3 += v * bf2f((ushort_t)(g[1] >> 16));
    }
    if (e < e1) {
      int ee = e + es;
      bool ok = ee < e1;
      int2 cv = ecv[ok ? ee : e1 - 1];
      float v = ok ? __int_as_float(cv.y) : 0.f;
      u32x2 g = *(const u32x2*)(G0 + (size_t)cv.x * 32 + fq);
      a0 += v * bf2f((ushort_t)g[0]);
      a1 += v * bf2f((ushort_t)(g[0] >> 16));
      a2 += v * bf2f((ushort_t)g[1]);
      a3 += v * bf2f((ushort_t)(g[1] >> 16));
    }
  }
  // reduce edge slots: lanes differing in bits 3,4,5
#pragma unroll
  for (int off = 8; off < 64; off <<= 1) {
    a0 += __shfl_xor(a0, off);
    a1 += __shfl_xor(a1, off);
    a2 += __shfl_xor(a2, off);
    a3 += __shfl_xor(a3, off);
  }

  if (MODE == 1) {
    if (lane < 8) {
      float t0 = (a0 >= 0.f) ? a0 : 0.2f * a0;
      float t1 = (a1 >= 0.f) ? a1 : 0.2f * a1;
      float t2 = (a2 >= 0.f) ? a2 : 0.2f * a2;
      float t3 = (a3 >= 0.f) ? a3 : 0.2f * a3;
      t0 = (keep0 && active) ? t0 * 1.25f : 0.f;
      t1 = (keep1 && active) ? t1 * 1.25f : 0.f;
      t2 = (keep2 && active) ? t2 * 1.25f : 0.f;
      t3 = (keep3 && active) ? t3 * 1.25f : 0.f;
      *(u32x2*)(stage + wave * 32 + lane * 4) = (u32x2){
          (unsigned int)f2bf(t0) | ((unsigned int)f2bf(t1) << 16),
          (unsigned int)f2bf(t2) | ((unsigned int)f2bf(t3) << 16)};
    }
    __syncthreads();
    // flush: frag chunk (16-row tile, kc=p). Our 4 rows (r0%4==0) occupy,
    // per quad, a contiguous 32-elem (64B) aligned segment. 32 thr x 8B.
    if (threadIdx.x < 32) {
      int quad = threadIdx.x >> 3, s = threadIdx.x & 7;
      int row = s >> 1, half = (s & 1) * 4;
      int r0 = rg * 4;
      size_t base = (size_t)(r0 >> 4) * 16 * D + ((size_t)p << 9) +
                    (size_t)quad * 128 + (size_t)((r0 & 15) + row) * 8 + half;
      *(u32x2*)((ushort_t*)outp + base) =
          *(const u32x2*)(stage + row * 32 + quad * 8 + half);
    }
  } else {
    if (active && lane < 8) {
      float4 o = make_float4(a0, a1, a2, a3);
      *(float4*)((float*)outp + (size_t)r * D + p * 32 + lane * 4) = o;
    }
  }
}

// ---------------- launch ----------------
extern "C" void kernel_launch(void* const* d_in, const int* in_sizes, int n_in,
                              void* d_out, int out_size, void* d_ws, size_t ws_size,
                              hipStream_t stream) {
  const void* x     = d_in[0];
  const int*  rows  = (const int*)d_in[1];
  const int*  cols  = (const int*)d_in[2];
  const void* vals  = d_in[3];
  const void* W1    = d_in[4];
  const void* b1    = d_in[5];
  const void* W2    = d_in[6];
  const void* b2    = d_in[7];
  const void* W3    = d_in[8];
  const void* b3    = d_in[9];
  const void* mask1 = d_in[10];
  const void* mask2 = d_in[11];

  const int H1  = in_sizes[5];            // 256
  const int H2  = in_sizes[7];            // 128
  const int OUT = in_sizes[9];            // 64
  const int IN  = in_sizes[4] / H1;       // 256
  const int N   = in_sizes[0] / IN;       // 50000
  const int E   = in_sizes[1];            // 800000
  const int W1n = in_sizes[4], W2n = in_sizes[6], W3n = in_sizes[8];
  const int Np  = ((N + 15) / 16) * 16;
  const int CAP = (E >> 5) + 2048;        // per-bin cap
  const int use_bins = (N <= 65535) ? 1 : 0;
  const int P = (N + 255) / 256;          // scan blocks (<=256 for lookback)

  char* ws = (char*)d_ws;
  size_t off = 0;
  auto alloc = [&](size_t bytes) -> void* {
    void* p = ws + off;
    off = (off + bytes + 255) & ~(size_t)255;
    return p;
  };
  int*      modes     = (int*)alloc(4 * 4);
  int*      row_start = (int*)alloc((size_t)(N + 1) * 4);
  // meta (zeroed): [h8: 8N | cnt_ovf: N | fill: N | binfill: 256 | pub: 256]
  int*      meta      = (int*)alloc(((size_t)10 * N + 512) * 4);
  int*      sb8       = (int*)alloc((size_t)9 * N * 4);        // cursor bases
  int2*     ecv       = (int2*)alloc((size_t)E * 8);
  int2*     bins      = (int2*)alloc((size_t)64 * CAP * 8);
  int4*     ovf       = (int4*)alloc((size_t)E * 16);
  ushort_t* whi       = (ushort_t*)alloc((size_t)(W1n + W2n + W3n) * 2);
  ushort_t* wlo       = (ushort_t*)alloc((size_t)(W1n + W2n + W3n) * 2);
  float*    biasf     = (float*)alloc((size_t)(H1 + H2 + OUT) * 4);
  ushort_t* bufA      = (ushort_t*)alloc((size_t)Np * H1 * 2);   // frag / G3
  ushort_t* bufB      = (ushort_t*)alloc((size_t)Np * H1 * 2);   // panel G
  // bufC ALIASED onto [bins|ovf] (bins dead after pass 2; bufC first written
  // by spmm1 which launches after scatter_gemm completes)
  ushort_t* bufC      = (ushort_t*)bins;
  // total ~89 MB (<=110 MB proven safe in r3)

  int* fmode   = modes;
  int* mm1     = modes + 1;
  int* mm2     = modes + 2;
  int* h8      = meta;                     // 8N (main: plain; fallback: atomic)
  int* cnt_ovf = meta + 8 * N;             // N
  int* fill    = meta + 9 * N;             // N (fallback only)
  int* binfill = meta + 10 * N;            // 128 bin ctrs + ovf ctr [128]
  int* pub     = meta + 10 * N + 256;      // 256 lookback slots
  ushort_t* w1hi = whi,             *w1lo = wlo;
  ushort_t* w2hi = whi + W1n,       *w2lo = wlo + W1n;
  ushort_t* w3hi = whi + W1n + W2n, *w3lo = wlo + W1n + W2n;

  // 1. prep: sniff + W/bias convert (self-sniff) + zero meta region
  prep_kernel<<<512, 256, 0, stream>>>(
      x, mask1, mask2, modes, meta, 10 * N + 512,
      W1, W2, W3, b1, b2, b3, whi, wlo, biasf,
      W1n, W2n, W3n, H1, H2, OUT, IN, H1, H2);

  // 2. binning (1024 blocks, no per-edge global atomics) + x-frag convert
  hist_bin_kernel<<<2048, 256, 0, stream>>>(
      rows, cols, vals, fmode, h8, cnt_ovf, binfill, bins, CAP, use_bins, ovf,
      E, N, x, bufA, IN, N * IN);

  // 3. per-(xcd,partition) LDS histogram -> h8 (no global atomics)
  count_kernel<<<64, 256, 0, stream>>>(bins, binfill, CAP, h8, N, use_bins);

  // 4. single-pass CSR scan (lookback) + shard cursor bases sb8
  scan_fused_kernel<<<P, 256, 0, stream>>>(h8, cnt_ovf, pub, row_start, sb8, N);

  // 5. pass 2 (atomic-free scatter, 64 blocks) || GEMM-1 (1024 blocks)
  //    GEMM-1 writes G1 panel-major into bufB.
  scatter_gemm_kernel<<<1088, 256, 0, stream>>>(
      bins, binfill, row_start, fill, sb8, N, ecv, CAP, ovf,
      rows, cols, vals, fmode, use_bins, E,
      bufA, (const ushort_t*)x, w1hi, w1lo, biasf, bufB, Np, N, H1 / 16);

  const int RGB4 = (N + 3) / 4;            // row-groups of 4
  const int GEMM_BLOCKS = 1024;

  // 6-10. panel-SpMM / GEMM chain
  // spmm1: G1(bufB, 8 panels) -> leaky+mask1 -> frag bufC (K=H1)
  spmmp_kernel<1><<<8 * RGB4, 256, 0, stream>>>(
      row_start, ecv, bufB, H1, Np, mask1, mm1, bufC, N, 8);
  // gemm2: bufC frag -> G2 panel-major (bufB, 4 panels)
  gemm_breg_kernel<8><<<GEMM_BLOCKS, 256, 0, stream>>>(
      bufC, nullptr, fmode, w2hi, w2lo, biasf + H1, bufB, Np, N, H2 / 16);
  // spmm2: G2 -> leaky+mask2 -> frag bufA (K=H2)
  spmmp_kernel<1><<<4 * RGB4, 256, 0, stream>>>(
      row_start, ecv, bufB, H2, Np, mask2, mm2, bufA, N, 4);
  // gemm3: bufA frag -> G3 panel-major (bufB, 2 panels)
  gemm_breg_kernel<4><<<GEMM_BLOCKS, 256, 0, stream>>>(
      bufA, nullptr, fmode, w3hi, w3lo, biasf + H1 + H2, bufB, Np, N, OUT / 16);
  // spmm3: G3 -> f32 row-major d_out
  spmmp_kernel<0><<<2 * RGB4, 256, 0, stream>>>(
      row_start, ecv, bufB, OUT, Np, nullptr, fmode, d_out, N, 2);
}

// Round 13
// 404.297 us; speedup vs baseline: 1.5045x; 1.5045x over previous
//
#include <hip/hip_runtime.h>

// ===========================================================================
// ViewGCNEncoder r28 = r25 verbatim (verified 409.1us). Reverts the r26/r27
// panel-major SpMM experiments per pre-committed falsifier: panel L2
// residency DID cut FETCH 208->93MB (mechanism confirmed twice) but cannot
// be converted to time at avg row length 16 (per-row fixed costs x npanel;
// r26 scalar loads 158us, r27 instruction-parity 199us vs spmm8's 66us).
// Structure: zero per-edge global atomics (LDS-hist binning + LDS-cursor
// scatter), single-pass lookback scan, pass2 scatter || GEMM-1 fusion,
// spmm8 at its 8xG compulsory-FETCH floor (208MB @ ~3.5TB/s).
// 10 launches. Workspace ~89 MB.
// ===========================================================================

typedef unsigned short ushort_t;
typedef __attribute__((ext_vector_type(8))) short bf16x8;   // 8 bf16 = 4 VGPRs
typedef __attribute__((ext_vector_type(4))) float f32x4;
typedef __attribute__((ext_vector_type(2))) unsigned int u32x2;
typedef __attribute__((ext_vector_type(4))) unsigned int u32x4;

__device__ __forceinline__ float bf2f(ushort_t u) {
  return __uint_as_float(((unsigned int)u) << 16);
}
__device__ __forceinline__ ushort_t f2bf(float f) {
  unsigned int u = __float_as_uint(f);
  return (ushort_t)((u + 0x7FFFu + ((u >> 16) & 1u)) >> 16);  // RNE
}
__device__ __forceinline__ float read_f(const void* p, int fm, size_t i) {
  return fm ? bf2f(((const ushort_t*)p)[i]) : ((const float*)p)[i];
}

// fragment-order offset: tile-major 16-row tiles; within tile kc-chunk(32 k)
// then lane-linear (lane = (m&15)+16*((k>>3)&3), 8 elems each).
__device__ __forceinline__ size_t frag_off(int m, int k, int K) {
  return (size_t)(m >> 4) * 16 * K + ((size_t)(k >> 5) << 9) +
         (((k >> 3) & 3) << 7) + ((m & 15) << 3) + (k & 7);
}

// ---------------- prep: sniff (0-2) + W/bias convert (3-34) + zero (35+) ---
__global__ void prep_kernel(const void* __restrict__ x,
                            const void* __restrict__ m1,
                            const void* __restrict__ m2,
                            int* __restrict__ modes,
                            int* __restrict__ zero_region, int zn,
                            const void* __restrict__ W1, const void* __restrict__ W2,
                            const void* __restrict__ W3,
                            const void* __restrict__ b1, const void* __restrict__ b2,
                            const void* __restrict__ b3,
                            ushort_t* __restrict__ whi, ushort_t* __restrict__ wlo,
                            float* __restrict__ biasf,
                            int n1, int n2, int n3, int h1, int h2, int h3,
                            int K1, int K2, int K3) {
  if (blockIdx.x == 0) {
    __shared__ int bfok;
    if (threadIdx.x == 0) bfok = 1;
    __syncthreads();
    for (int i = threadIdx.x; i < 8192; i += blockDim.x) {
      ushort_t h = ((const ushort_t*)x)[i];
      int e = (h >> 7) & 0xFF;
      if (!(h == 0 || (e >= 95 && e <= 133))) atomicAnd(&bfok, 0);
    }
    __syncthreads();
    if (threadIdx.x == 0) modes[0] = bfok;   // 1=bf16, 0=f32
  } else if (blockIdx.x <= 2) {
    const void* p = (blockIdx.x == 1) ? m1 : m2;
    __shared__ int ok[4];  // [i32, f32, bf16, u8]
    if (threadIdx.x < 4) ok[threadIdx.x] = 1;
    __syncthreads();
    for (int i = threadIdx.x; i < 4096; i += blockDim.x) {
      unsigned int w = ((const unsigned int*)p)[i];
      if (!(w == 0u || w == 1u)) atomicAnd(&ok[0], 0);
      if (!(w == 0u || w == 0x3F800000u)) atomicAnd(&ok[1], 0);
      unsigned int h16 = w >> 16, l16 = w & 0xFFFFu;
      if (!((h16 == 0u || h16 == 0x3F80u) && (l16 == 0u || l16 == 0x3F80u)))
        atomicAnd(&ok[2], 0);
      if (((w | (w >> 8) | (w >> 16) | (w >> 24)) & 0xFEu) != 0u) atomicAnd(&ok[3], 0);
    }
    __syncthreads();
    if (threadIdx.x == 0)
      modes[blockIdx.x] = ok[0] ? 1 : (ok[1] ? 2 : (ok[2] ? 3 : 0));
  } else if (blockIdx.x < 35) {
    // W split + bias convert; self-sniff x dtype (weights share x's dtype)
    __shared__ int bfok;
    if (threadIdx.x == 0) bfok = 1;
    __syncthreads();
    for (int i = threadIdx.x; i < 8192; i += blockDim.x) {
      ushort_t h = ((const ushort_t*)x)[i];
      int e = (h >> 7) & 0xFF;
      if (!(h == 0 || (e >= 95 && e <= 133))) atomicAnd(&bfok, 0);
    }
    __syncthreads();
    int fm = bfok;
    int wtot = n1 + n2 + n3;
    int total = wtot + h1 + h2 + h3;
    for (int i = (blockIdx.x - 3) * 256 + threadIdx.x; i < total; i += 32 * 256) {
      if (i < wtot) {
        const void* src; int j, K; size_t base;
        if (i < n1) { src = W1; j = i; K = K1; base = 0; }
        else if (i < n1 + n2) { src = W2; j = i - n1; K = K2; base = n1; }
        else { src = W3; j = i - n1 - n2; K = K3; base = (size_t)n1 + n2; }
        int n = j / K, k = j - n * K;
        float v = read_f(src, fm, j);
        ushort_t h = f2bf(v);
        size_t o = base + frag_off(n, k, K);
        whi[o] = h;
        wlo[o] = f2bf(v - bf2f(h));
      } else {
        int k = i - wtot;
        const void* src; int j;
        if (k < h1) { src = b1; j = k; }
        else if (k < h1 + h2) { src = b2; j = k - h1; }
        else { src = b3; j = k - h1 - h2; }
        biasf[k] = read_f(src, fm, j);
      }
    }
  } else {
    int i = (blockIdx.x - 35) * blockDim.x + threadIdx.x;
    int stride = (gridDim.x - 35) * blockDim.x;
    for (; i < zn; i += stride) zero_region[i] = 0;
  }
}

// ---------------- pass 1: tile-binning, LDS-staged flush (no edge atomics) --
__global__ void hist_bin_kernel(
    const int* __restrict__ rows, const int* __restrict__ cols,
    const void* __restrict__ vals, const int* __restrict__ fm_p,
    int* __restrict__ h8, int* __restrict__ cnt_ovf, int* __restrict__ binfill,
    int2* __restrict__ bins, int cap, int use_bins, int4* __restrict__ ovf,
    int E, int Nrows, const void* __restrict__ x, ushort_t* __restrict__ xbf,
    int K1, int nx) {
  int fm = *fm_p;
  const int BIN_BLOCKS = 1024;
  if (blockIdx.x < BIN_BLOCKS) {
    int xcd = blockIdx.x & 7;
    if (use_bins) {
      __shared__ int hist[8];
      __shared__ int gbase[8];
      __shared__ int pfx[8];
      __shared__ int2 stage[1024];
      int tid = threadIdx.x;
      for (int tb = blockIdx.x; tb * 1024 < E; tb += BIN_BLOCKS) {
        int base = tb * 1024;
        if (tid < 8) hist[tid] = 0;
        __syncthreads();
        int rr[4], cc[4], pp[4], rk[4]; float vv[4];
#pragma unroll
        for (int j = 0; j < 4; ++j) {
          int i = base + j * 256 + tid;
          if (i < E) {
            rr[j] = rows[i]; cc[j] = cols[i]; vv[j] = read_f(vals, fm, i);
            pp[j] = rr[j] >> 13;                   // partition 0..7
            rk[j] = atomicAdd(&hist[pp[j]], 1);    // LDS rank
          } else {
            pp[j] = -1;
          }
        }
        __syncthreads();
        if (tid == 0) {
          int s = 0;
#pragma unroll
          for (int q = 0; q < 8; ++q) { pfx[q] = s; s += hist[q]; }
        }
        if (tid < 8)
          gbase[tid] = atomicAdd(&binfill[(xcd << 4) + tid], hist[tid]);
        __syncthreads();
        // stage partition-sorted
#pragma unroll
        for (int j = 0; j < 4; ++j) {
          if (pp[j] >= 0)
            stage[pfx[pp[j]] + rk[j]] =
                make_int2((rr[j] << 16) | cc[j], __float_as_int(vv[j]));
        }
        __syncthreads();
        // coalesced flush
        int total = pfx[7] + hist[7];
        for (int k = tid; k < total; k += 256) {
          int p = 0;
#pragma unroll
          for (int q = 1; q < 8; ++q) p += (k >= pfx[q]);
          int2 ent = stage[k];
          int pos = gbase[p] + (k - pfx[p]);
          if (pos < cap) {
            bins[(size_t)((xcd << 3) + p) * cap + pos] = ent;
          } else {  // overflow (skewed rows): pre-assign rank, append to ovf
            int r = ((unsigned int)ent.x) >> 16;
            int orank = atomicAdd(&cnt_ovf[r], 1);
            int op = atomicAdd(&binfill[128], 1);
            ovf[op] = make_int4(r, ent.x & 0xFFFF, ent.y, orank);
          }
        }
        __syncthreads();            // protect pfx/hist before next tile
      }
    } else {
      // fallback (N > 65535): sharded atomic hist; pass 2 direct-scatters
      int* cnt_s = h8 + (size_t)xcd * Nrows;
      int i = blockIdx.x * blockDim.x + threadIdx.x;
      int stride = BIN_BLOCKS * blockDim.x;
      for (; i < E; i += stride) atomicAdd(&cnt_s[rows[i]], 1);
    }
  } else {
    // x -> bf16 frag conversion (only when x is f32)
    if (fm == 1) return;
    int nx4 = nx / 4;
    int i = (blockIdx.x - BIN_BLOCKS) * blockDim.x + threadIdx.x;
    int stride = (gridDim.x - BIN_BLOCKS) * blockDim.x;
    for (; i < nx4; i += stride) {
      int m = i / (K1 / 4);
      int k0 = (i - m * (K1 / 4)) * 4;
      f32x4 v = ((const f32x4*)x)[i];
      ushort_t p0 = f2bf(v[0]), p1 = f2bf(v[1]), p2 = f2bf(v[2]), p3 = f2bf(v[3]);
      size_t o = frag_off(m, k0, K1);
      *(u32x2*)(xbf + o) = (u32x2){
          (unsigned int)p0 | ((unsigned int)p1 << 16),
          (unsigned int)p2 | ((unsigned int)p3 << 16)};
    }
  }
}

// ---------------- pass 1.5: per-(xcd,partition) LDS histogram -> h8 ---------
__global__ __launch_bounds__(256) void count_kernel(
    const int2* __restrict__ bins, const int* __restrict__ binfill,
    int cap, int* __restrict__ h8, int Nrows, int use_bins) {
  if (!use_bins) return;
  int x = blockIdx.x >> 3, p = blockIdx.x & 7;
  __shared__ int hist[8192];
  for (int i = threadIdx.x; i < 8192; i += 256) hist[i] = 0;
  __syncthreads();
  int n = binfill[x * 16 + p];
  if (n > cap) n = cap;
  const int2* bp = bins + (size_t)((x << 3) + p) * cap;
  for (int e = threadIdx.x; e < n; e += 256) {
    int r = ((unsigned int)bp[e].x) >> 16;
    atomicAdd(&hist[r & 8191], 1);
  }
  __syncthreads();
  int r0 = p << 13;
  for (int i = threadIdx.x; i < 8192; i += 256) {
    int r = r0 + i;
    if (r < Nrows) h8[(size_t)x * Nrows + r] = hist[i];
  }
}

// ---------------- single-pass scan: shard-sum + lookback + cursor bases -----
__global__ __launch_bounds__(256) void scan_fused_kernel(
    const int* __restrict__ h8, const int* __restrict__ cnt_ovf,
    int* __restrict__ pub, int* __restrict__ row_start,
    int* __restrict__ sb8, int n) {
  int b = blockIdx.x, t = threadIdx.x;
  int i = b * 256 + t;
  int hx[8];
  int v = 0, ov = 0;
  if (i < n) {
#pragma unroll
    for (int x = 0; x < 8; ++x) { hx[x] = h8[(size_t)x * n + i]; v += hx[x]; }
    ov = cnt_ovf[i];
  } else {
#pragma unroll
    for (int x = 0; x < 8; ++x) hx[x] = 0;
  }
  int vt = v + ov;
  __shared__ int s[256];
  s[t] = vt;
  __syncthreads();
  for (int off = 1; off < 256; off <<= 1) {
    int a_ = s[t];
    int y_ = (t >= off) ? s[t - off] : 0;
    __syncthreads();
    s[t] = a_ + y_;
    __syncthreads();
  }
  int incl = s[t];
  int total = s[255];
  if (t == 0)
    __hip_atomic_store(&pub[b], (total << 1) | 1, __ATOMIC_RELEASE,
                       __HIP_MEMORY_SCOPE_AGENT);
  int contrib = 0;
  for (int t0 = t; t0 < b; t0 += 256) {
    int p;
    do {
      p = __hip_atomic_load(&pub[t0], __ATOMIC_ACQUIRE,
                            __HIP_MEMORY_SCOPE_AGENT);
    } while (!(p & 1));
    contrib += (p >> 1);
  }
  __syncthreads();                 // s[] reuse barrier
  s[t] = contrib;
  __syncthreads();
  for (int off = 128; off > 0; off >>= 1) {
    if (t < off) s[t] += s[t + off];
    __syncthreads();
  }
  int base = s[0];
  int rs = base + incl - vt;       // exclusive
  if (i < n) {
    row_start[i] = rs;
    int acc = rs;
#pragma unroll
    for (int x = 0; x < 8; ++x) { sb8[(size_t)x * n + i] = acc; acc += hx[x]; }
    sb8[(size_t)8 * n + i] = acc;  // ovf base
  }
  if (i == n - 1) row_start[n] = base + incl;
}

// ---------------- GEMM body (frozen r15 core, device-callable) --------------
template<int KC>
__device__ __forceinline__ void load_afrag(const ushort_t* __restrict__ A,
                                           const ushort_t* __restrict__ Xrow,
                                           bool rowA, int mtile, int K,
                                           int lane, int mr, int quad, int M,
                                           bf16x8* dst) {
  if (rowA) {
    int rr = mtile * 16 + mr;
    if (rr >= M) rr = M - 1;
    const ushort_t* ap = Xrow + (size_t)rr * K + quad * 8;
#pragma unroll
    for (int kc = 0; kc < KC; ++kc) dst[kc] = *(const bf16x8*)(ap + kc * 32);
  } else {
    const ushort_t* ap = A + (size_t)mtile * 16 * K + lane * 8;
#pragma unroll
    for (int kc = 0; kc < KC; ++kc) dst[kc] = *(const bf16x8*)(ap + kc * 512);
  }
}

template<int KC>
__device__ __forceinline__ void gemm_dev(
    int vbid, int nblk, int tid,
    const ushort_t* __restrict__ A, const ushort_t* __restrict__ Xrow, int fm,
    const ushort_t* __restrict__ Whi, const ushort_t* __restrict__ Wlo,
    const float* __restrict__ bias, ushort_t* __restrict__ g, int ldg,
    int M, int nct) {
  const int K = KC * 32;
  int wave = tid >> 6, lane = tid & 63;
  int gw = vbid * 4 + wave;
  int NW = nblk * 4;
  int mr = lane & 15, quad = lane >> 4;
  int ct = gw % nct;
  int nrt = (M + 15) >> 4;
  int ntasks = nct * nrt;
  if (gw >= ntasks) return;

  bool rowA = (Xrow != nullptr) && (fm != 0);

  bf16x8 wh[KC], wl[KC];
  {
    const ushort_t* wp = Whi + (size_t)ct * 16 * K + lane * 8;
    const ushort_t* wq = Wlo + (size_t)ct * 16 * K + lane * 8;
#pragma unroll
    for (int kc = 0; kc < KC; ++kc) {
      wh[kc] = *(const bf16x8*)(wp + kc * 512);
      wl[kc] = *(const bf16x8*)(wq + kc * 512);
    }
  }
  int col = ct * 16 + mr;
  float bv = bias[col];

  int task = gw;
  bf16x8 af[KC];
  load_afrag<KC>(A, Xrow, rowA, task / nct, K, lane, mr, quad, M, af);

#pragma unroll 1
  for (;;) {
    int next = task + NW;
    bool has_next = next < ntasks;
    bf16x8 afn[KC];
    if (has_next)
      load_afrag<KC>(A, Xrow, rowA, next / nct, K, lane, mr, quad, M, afn);

    f32x4 acc[4];
#pragma unroll
    for (int t = 0; t < 4; ++t) acc[t] = (f32x4){0.f, 0.f, 0.f, 0.f};
#pragma unroll
    for (int kc = 0; kc < KC; ++kc) {
      acc[(2 * kc) & 3] = __builtin_amdgcn_mfma_f32_16x16x32_bf16(af[kc], wh[kc], acc[(2 * kc) & 3], 0, 0, 0);
      acc[(2 * kc + 1) & 3] = __builtin_amdgcn_mfma_f32_16x16x32_bf16(af[kc], wl[kc], acc[(2 * kc + 1) & 3], 0, 0, 0);
    }
    int m0 = (task / nct) * 16;
#pragma unroll
    for (int r = 0; r < 4; ++r) {
      int row = m0 + quad * 4 + r;
      float s = ((acc[0][r] + acc[1][r]) + (acc[2][r] + acc[3][r])) + bv;
      if (row < M) g[(size_t)row * ldg + col] = f2bf(s);
    }
    if (!has_next) break;
#pragma unroll
    for (int kc = 0; kc < KC; ++kc) af[kc] = afn[kc];
    task = next;
  }
}

template<int KC>
__global__ __launch_bounds__(256) void gemm_breg_kernel(
    const ushort_t* __restrict__ A,
    const ushort_t* __restrict__ Xrow, const int* __restrict__ fm_p,
    const ushort_t* __restrict__ Whi, const ushort_t* __restrict__ Wlo,
    const float* __restrict__ bias, ushort_t* __restrict__ g, int ldg,
    int M, int nct) {
  gemm_dev<KC>(blockIdx.x, gridDim.x, threadIdx.x, A, Xrow, *fm_p,
               Whi, Wlo, bias, g, ldg, M, nct);
}

// ---------------- pass 2 (atomic-free scatter, blocks 0..63) + GEMM-1 -------
__global__ __launch_bounds__(256) void scatter_gemm_kernel(
    const int2* __restrict__ bins, const int* __restrict__ binfill,
    const int* __restrict__ row_start, int* __restrict__ fill,
    const int* __restrict__ sb8, int Nrows,
    int2* __restrict__ ecv, int cap, const int4* __restrict__ ovf,
    const int* __restrict__ rows, const int* __restrict__ cols,
    const void* __restrict__ vals, const int* __restrict__ fm_p,
    int use_bins, int E,
    const ushort_t* __restrict__ A, const ushort_t* __restrict__ Xrow,
    const ushort_t* __restrict__ Whi, const ushort_t* __restrict__ Wlo,
    const float* __restrict__ bias, ushort_t* __restrict__ g, int ldg,
    int M, int nct) {
  __shared__ int sbl[8192];
  if (blockIdx.x >= 64) {
    gemm_dev<8>(blockIdx.x - 64, 1024, threadIdx.x, A, Xrow, *fm_p,
                Whi, Wlo, bias, g, ldg, M, nct);
    return;
  }
  if (use_bins) {
    int x = blockIdx.x >> 3, p = blockIdx.x & 7;
    int r0 = p << 13;
    for (int i = threadIdx.x; i < 8192; i += 256) {
      int r = r0 + i;
      sbl[i] = (r < Nrows) ? sb8[(size_t)x * Nrows + r] : 0;
    }
    __syncthreads();
    int n = binfill[x * 16 + p];
    if (n > cap) n = cap;
    const int2* bp = bins + (size_t)((x << 3) + p) * cap;
    for (int e = threadIdx.x; e < n; e += 256) {
      int2 ent = bp[e];
      int r = ((unsigned int)ent.x) >> 16;
      int pos = atomicAdd(&sbl[r & 8191], 1);     // LDS cursor, no global RMW
      ecv[pos] = make_int2(ent.x & 0xFFFF, ent.y);
    }
    // ovf drain (rank pre-assigned in pass 1; no atomics)
    int ovfn = binfill[128];
    for (int e = blockIdx.x * 256 + (int)threadIdx.x; e < ovfn; e += 64 * 256) {
      int4 t = ovf[e];
      ecv[sb8[(size_t)8 * Nrows + t.x] + t.w] = make_int2(t.y, t.z);
    }
  } else {
    int fm = *fm_p;
    for (int i = blockIdx.x * 256 + (int)threadIdx.x; i < E; i += 64 * 256) {
      int r = rows[i];
      int pos = atomicAdd(&fill[r], 1);
      ecv[row_start[r] + pos] = make_int2(cols[i], __float_as_int(read_f(vals, fm, i)));
    }
  }
}

// ---------------- SpMM v9: deep-MLP gathers (frozen r21) --------------------
template<int VEC, int CHUNK, bool CLAMP>
__device__ __forceinline__ void spmm_chunk(const int2* __restrict__ ecv,
                                           int base, int e1,
                                           const ushort_t* __restrict__ G,
                                           int D, int f0, float* a) {
  int2 cv[CHUNK];
#pragma unroll
  for (int j = 0; j < CHUNK; ++j) {
    int ee = base + j;
    if (CLAMP) ee = (ee < e1) ? ee : e1 - 1;
    cv[j] = ecv[ee];
  }
  float v[CHUNK];
#pragma unroll
  for (int j = 0; j < CHUNK; ++j) {
    v[j] = __int_as_float(cv[j].y);
    if (CLAMP && (base + j >= e1)) v[j] = 0.f;
  }
  if (VEC == 4) {
    u32x2 gg[CHUNK];
#pragma unroll
    for (int j = 0; j < CHUNK; ++j)
      gg[j] = *(const u32x2*)(G + (size_t)cv[j].x * D + f0);
#pragma unroll
    for (int j = 0; j < CHUNK; ++j) {
      a[0] += v[j] * bf2f((ushort_t)gg[j][0]);
      a[1] += v[j] * bf2f((ushort_t)(gg[j][0] >> 16));
      a[2] += v[j] * bf2f((ushort_t)gg[j][1]);
      a[3] += v[j] * bf2f((ushort_t)(gg[j][1] >> 16));
    }
  } else if (VEC == 2) {
    unsigned int gg[CHUNK];
#pragma unroll
    for (int j = 0; j < CHUNK; ++j)
      gg[j] = *(const unsigned int*)(G + (size_t)cv[j].x * D + f0);
#pragma unroll
    for (int j = 0; j < CHUNK; ++j) {
      a[0] += v[j] * bf2f((ushort_t)gg[j]);
      a[1] += v[j] * bf2f((ushort_t)(gg[j] >> 16));
    }
  } else {
    ushort_t h[CHUNK];
#pragma unroll
    for (int j = 0; j < CHUNK; ++j) h[j] = G[(size_t)cv[j].x * D + f0];
#pragma unroll
    for (int j = 0; j < CHUNK; ++j) a[0] += v[j] * bf2f(h[j]);
  }
}

template<int MODE, int VEC>
__global__ __launch_bounds__(256) void spmm8_kernel(
    const int* __restrict__ row_start, const int2* __restrict__ ecv,
    const ushort_t* __restrict__ G, int D,
    const void* __restrict__ mask, const int* __restrict__ mmode_p,
    void* __restrict__ outp, int N) {
  __shared__ ushort_t stage[1024];         // 4 rows x up to 256 cols
  int wave = threadIdx.x >> 6, lane = threadIdx.x & 63;
  int r = blockIdx.x * 4 + wave;
  bool active = r < N;
  float a[VEC];
#pragma unroll
  for (int q = 0; q < VEC; ++q) a[q] = 0.f;
  int f0 = lane * VEC;

  // ---- hoisted mask load (independent of gather chain) ----
  bool keep[VEC];
#pragma unroll
  for (int q = 0; q < VEC; ++q) keep[q] = true;
  if (MODE == 1 && active) {
    size_t om = (size_t)r * D + f0;        // mask is row-major
    int mm = *mmode_p;
    if (mm == 1 || mm == 2) {              // 4B/elem: vector load
      if (VEC == 4) {
        u32x4 mv = *(const u32x4*)((const unsigned int*)mask + om);
#pragma unroll
        for (int q = 0; q < VEC; ++q) keep[q] = mv[q] != 0u;
      } else if (VEC == 2) {
        u32x2 mv = *(const u32x2*)((const unsigned int*)mask + om);
#pragma unroll
        for (int q = 0; q < VEC; ++q) keep[q] = mv[q] != 0u;
      } else {
        keep[0] = ((const unsigned int*)mask)[om] != 0u;
      }
    } else if (mm == 3) {                  // bf16: vector load
      if (VEC == 4) {
        u32x2 mv = *(const u32x2*)((const ushort_t*)mask + om);
        keep[0] = (mv[0] & 0xFFFFu) != 0u; keep[1] = (mv[0] >> 16) != 0u;
        keep[2] = (mv[1] & 0xFFFFu) != 0u; keep[3] = (mv[1] >> 16) != 0u;
      } else if (VEC == 2) {
        unsigned int mv = *(const unsigned int*)((const ushort_t*)mask + om);
        keep[0] = (mv & 0xFFFFu) != 0u; keep[1] = (mv >> 16) != 0u;
      } else {
        keep[0] = ((const ushort_t*)mask)[om] != 0;
      }
    } else {                               // u8: vector load
      if (VEC == 4) {
        unsigned int mv = *(const unsigned int*)((const unsigned char*)mask + om);
        keep[0] = (mv & 0xFFu) != 0u;         keep[1] = ((mv >> 8) & 0xFFu) != 0u;
        keep[2] = ((mv >> 16) & 0xFFu) != 0u; keep[3] = (mv >> 24) != 0u;
      } else if (VEC == 2) {
        unsigned int mv = *(const unsigned short*)((const unsigned char*)mask + om);
        keep[0] = (mv & 0xFFu) != 0u; keep[1] = ((mv >> 8) & 0xFFu) != 0u;
      } else {
        keep[0] = ((const unsigned char*)mask)[om] != 0;
      }
    }
  }

  if (active) {
    int e  = __builtin_amdgcn_readfirstlane(row_start[r]);
    int e1 = __builtin_amdgcn_readfirstlane(row_start[r + 1]);
    for (; e + 16 <= e1; e += 16)
      spmm_chunk<VEC, 16, false>(ecv, e, e1, G, D, f0, a);
    for (; e < e1; e += 8)
      spmm_chunk<VEC, 8, true>(ecv, e, e1, G, D, f0, a);
  }

  if (MODE == 1) {
    if (active) {
#pragma unroll
      for (int q = 0; q < VEC; ++q) {
        float t = a[q];
        t = (t >= 0.f) ? t : 0.2f * t;             // leaky relu 0.2
        t = keep[q] ? t * 1.25f : 0.f;             // keep = 1/(1-0.2)
        stage[wave * D + f0 + q] = f2bf(t);
      }
    }
    __syncthreads();
    // flush: D threads, one 8B (4-elem) piece each; 64B line = 4 rows' chunks
    if (threadIdx.x < D) {
      int g = threadIdx.x >> 3, s = threadIdx.x & 7;   // group, sub
      int kc = g >> 2, quad = g & 3;
      int sr = s >> 1;                                  // source row in block
      int r0 = blockIdx.x * 4;
      if (r0 + sr < N) {
        int kk = kc * 32 + quad * 8 + (s & 1) * 4;
        size_t dst = (size_t)(r0 >> 4) * 16 * D + ((size_t)kc << 9) +
                     (quad << 7) + ((r0 & 15) << 3) + s * 4;
        *(u32x2*)((ushort_t*)outp + dst) = *(const u32x2*)(stage + sr * D + kk);
      }
    }
  } else {
    if (active) {
      size_t o = (size_t)r * D + f0;
#pragma unroll
      for (int q = 0; q < VEC; ++q) ((float*)outp)[o + q] = a[q];
    }
  }
}

// ---------------- launch ----------------
extern "C" void kernel_launch(void* const* d_in, const int* in_sizes, int n_in,
                              void* d_out, int out_size, void* d_ws, size_t ws_size,
                              hipStream_t stream) {
  const void* x     = d_in[0];
  const int*  rows  = (const int*)d_in[1];
  const int*  cols  = (const int*)d_in[2];
  const void* vals  = d_in[3];
  const void* W1    = d_in[4];
  const void* b1    = d_in[5];
  const void* W2    = d_in[6];
  const void* b2    = d_in[7];
  const void* W3    = d_in[8];
  const void* b3    = d_in[9];
  const void* mask1 = d_in[10];
  const void* mask2 = d_in[11];

  const int H1  = in_sizes[5];            // 256
  const int H2  = in_sizes[7];            // 128
  const int OUT = in_sizes[9];            // 64
  const int IN  = in_sizes[4] / H1;       // 256
  const int N   = in_sizes[0] / IN;       // 50000
  const int E   = in_sizes[1];            // 800000
  const int W1n = in_sizes[4], W2n = in_sizes[6], W3n = in_sizes[8];
  const int Np  = ((N + 15) / 16) * 16;
  const int CAP = (E >> 5) + 2048;        // per-bin cap
  const int use_bins = (N <= 65535) ? 1 : 0;
  const int P = (N + 255) / 256;          // scan blocks (<=256 for lookback)

  char* ws = (char*)d_ws;
  size_t off = 0;
  auto alloc = [&](size_t bytes) -> void* {
    void* p = ws + off;
    off = (off + bytes + 255) & ~(size_t)255;
    return p;
  };
  int*      modes     = (int*)alloc(4 * 4);
  int*      row_start = (int*)alloc((size_t)(N + 1) * 4);
  // meta (zeroed): [h8: 8N | cnt_ovf: N | fill: N | binfill: 256 | pub: 256]
  int*      meta      = (int*)alloc(((size_t)10 * N + 512) * 4);
  int*      sb8       = (int*)alloc((size_t)9 * N * 4);        // cursor bases
  int2*     ecv       = (int2*)alloc((size_t)E * 8);
  int2*     bins      = (int2*)alloc((size_t)64 * CAP * 8);
  int4*     ovf       = (int4*)alloc((size_t)E * 16);
  ushort_t* whi       = (ushort_t*)alloc((size_t)(W1n + W2n + W3n) * 2);
  ushort_t* wlo       = (ushort_t*)alloc((size_t)(W1n + W2n + W3n) * 2);
  float*    biasf     = (float*)alloc((size_t)(H1 + H2 + OUT) * 4);
  ushort_t* bufA      = (ushort_t*)alloc((size_t)Np * H1 * 2);   // frag
  ushort_t* bufB      = (ushort_t*)alloc((size_t)Np * H1 * 2);   // row-major G
  // bufC ALIASED onto [bins|ovf] (bins dead after pass 2; bufC first written
  // by spmm1 which launches after scatter_gemm completes)
  ushort_t* bufC      = (ushort_t*)bins;
  // total ~89 MB (<=110 MB proven safe in r3)

  int* fmode   = modes;
  int* mm1     = modes + 1;
  int* mm2     = modes + 2;
  int* h8      = meta;                     // 8N (main: plain; fallback: atomic)
  int* cnt_ovf = meta + 8 * N;             // N
  int* fill    = meta + 9 * N;             // N (fallback only)
  int* binfill = meta + 10 * N;            // 128 bin ctrs + ovf ctr [128]
  int* pub     = meta + 10 * N + 256;      // 256 lookback slots
  ushort_t* w1hi = whi,             *w1lo = wlo;
  ushort_t* w2hi = whi + W1n,       *w2lo = wlo + W1n;
  ushort_t* w3hi = whi + W1n + W2n, *w3lo = wlo + W1n + W2n;

  // 1. prep: sniff + W/bias convert (self-sniff) + zero meta region
  prep_kernel<<<512, 256, 0, stream>>>(
      x, mask1, mask2, modes, meta, 10 * N + 512,
      W1, W2, W3, b1, b2, b3, whi, wlo, biasf,
      W1n, W2n, W3n, H1, H2, OUT, IN, H1, H2);

  // 2. binning (1024 blocks, no per-edge global atomics) + x-frag convert
  hist_bin_kernel<<<2048, 256, 0, stream>>>(
      rows, cols, vals, fmode, h8, cnt_ovf, binfill, bins, CAP, use_bins, ovf,
      E, N, x, bufA, IN, N * IN);

  // 3. per-(xcd,partition) LDS histogram -> h8 (no global atomics)
  count_kernel<<<64, 256, 0, stream>>>(bins, binfill, CAP, h8, N, use_bins);

  // 4. single-pass CSR scan (lookback) + shard cursor bases sb8
  scan_fused_kernel<<<P, 256, 0, stream>>>(h8, cnt_ovf, pub, row_start, sb8, N);

  // 5. pass 2 (atomic-free scatter, 64 blocks) || GEMM-1 (1024 blocks)
  scatter_gemm_kernel<<<1088, 256, 0, stream>>>(
      bins, binfill, row_start, fill, sb8, N, ecv, CAP, ovf,
      rows, cols, vals, fmode, use_bins, E,
      bufA, (const ushort_t*)x, w1hi, w1lo, biasf, bufB, H1, N, H1 / 16);

  int spmm_grid = (N + 3) / 4;
  const int GEMM_BLOCKS = 1024;

  // 6-10. SpMM/GEMM chain
  spmm8_kernel<1, 4><<<spmm_grid, 256, 0, stream>>>(
      row_start, ecv, bufB, H1, mask1, mm1, bufC, N);
  gemm_breg_kernel<8><<<GEMM_BLOCKS, 256, 0, stream>>>(
      bufC, nullptr, fmode, w2hi, w2lo, biasf + H1, bufB, H2, N, H2 / 16);
  spmm8_kernel<1, 2><<<spmm_grid, 256, 0, stream>>>(
      row_start, ecv, bufB, H2, mask2, mm2, bufA, N);
  gemm_breg_kernel<4><<<GEMM_BLOCKS, 256, 0, stream>>>(
      bufA, nullptr, fmode, w3hi, w3lo, biasf + H1 + H2, bufB, OUT, N, OUT / 16);
  spmm8_kernel<0, 1><<<spmm_grid, 256, 0, stream>>>(
      row_start, ecv, bufB, OUT, nullptr, fmode, d_out, N);
}